// Round 7
// baseline (289.116 us; speedup 1.0000x reference)
//
#include <hip/hip_runtime.h>
#include <hip/hip_bf16.h>

#define N_NODES 50000
#define N_EDGES 800000
#define C 128

#define NBB   391      // buckets of 128 nodes: bucket = dst >> 7
#define CAPB  2600     // per-bucket capacity (mean 2046, +12 sigma)
#define CHUNK 2048     // edges per binA block

// ---------------------------------------------------------------------------
// k_binA: single-level radix partition (unchanged from round 6).
// ---------------------------------------------------------------------------
__global__ __launch_bounds__(256) void k_binA(const int* __restrict__ ei,
                                              int* __restrict__ gcur,
                                              int2* __restrict__ tmp) {
    __shared__ int hist[NBB];
    __shared__ int lbase[NBB];
    __shared__ int gbaseL[NBB];
    __shared__ int stmp[256];
    __shared__ int2 buf[CHUNK];
    __shared__ int totalv;

    int tid = threadIdx.x;
    int e0 = blockIdx.x * CHUNK;

    for (int i = tid; i < NBB; i += 256) hist[i] = 0;
    __syncthreads();

    int sarr[8], darr[8], parr[8];
#pragma unroll
    for (int j = 0; j < 8; ++j) {
        int e = e0 + j * 256 + tid;
        darr[j] = -1;
        if (e < N_EDGES) {
            sarr[j] = ei[e];
            int d = ei[N_EDGES + e];
            darr[j] = d;
            parr[j] = atomicAdd(&hist[d >> 7], 1);
        }
    }
    __syncthreads();

    // exclusive scan of hist (pairs: thread t owns buckets 2t, 2t+1)
    {
        int i0 = 2 * tid, i1 = 2 * tid + 1;
        int c0 = (i0 < NBB) ? hist[i0] : 0;
        int c1 = (i1 < NBB) ? hist[i1] : 0;
        int c = c0 + c1;
        stmp[tid] = c;
        __syncthreads();
        int v = c;
        for (int d = 1; d < 256; d <<= 1) {
            int w = (tid >= d) ? stmp[tid - d] : 0;
            __syncthreads();
            v += w;
            stmp[tid] = v;
            __syncthreads();
        }
        int excl = v - c;
        if (i0 < NBB) lbase[i0] = excl;
        if (i1 < NBB) lbase[i1] = excl + c0;
        if (tid == 255) totalv = v;
    }
    // reserve global runs (one atomic per non-empty bucket per block)
    for (int i = tid; i < NBB; i += 256) {
        int cnt = hist[i];
        int run = (cnt > 0) ? atomicAdd(&gcur[i], cnt) : 0;
        gbaseL[i] = i * CAPB + run;
    }
    __syncthreads();

    // LDS scatter
#pragma unroll
    for (int j = 0; j < 8; ++j) {
        if (darr[j] >= 0) {
            int b = darr[j] >> 7;
            buf[lbase[b] + parr[j]] = make_int2(sarr[j], darr[j]);
        }
    }
    __syncthreads();

    // coalesced write-out of per-bucket runs
    int total = totalv;
    for (int i = tid; i < total; i += 256) {
        int2 v = buf[i];
        int b = v.y >> 7;
        int gpos = gbaseL[b] + (i - lbase[b]);
        if (gpos < (b + 1) * CAPB) tmp[gpos] = v;   // overflow safety
    }
}

// ---------------------------------------------------------------------------
// k_dinv: per-node in-degree from the bucket, write dinv = rsqrt(deg+1).
// ---------------------------------------------------------------------------
__global__ __launch_bounds__(256) void k_dinv(const int2* __restrict__ tmp,
                                              const int* __restrict__ gcur,
                                              float* __restrict__ dinv) {
    __shared__ int cnt[128];
    int b = blockIdx.x, tid = threadIdx.x;
    if (tid < 128) cnt[tid] = 0;
    __syncthreads();
    int n = gcur[b];
    if (n > CAPB) n = CAPB;
    for (int i = tid; i < n; i += 256)
        atomicAdd(&cnt[tmp[b * CAPB + i].y & 127], 1);
    __syncthreads();
    int node = b * 128 + tid;
    if (tid < 128 && node < N_NODES)
        dinv[node] = rsqrtf((float)cnt[tid] + 1.0f);
}

// ---------------------------------------------------------------------------
// bf16 pack helpers (RTN)
// ---------------------------------------------------------------------------
__device__ __forceinline__ unsigned int bf16rtn(float f) {
    unsigned int u = __float_as_uint(f);
    return (u + 0x7fffu + ((u >> 16) & 1u)) >> 16;
}
__device__ __forceinline__ unsigned int packbf2(float lo, float hi) {
    return bf16rtn(lo) | (bf16rtn(hi) << 16);
}

// ---------------------------------------------------------------------------
// f32 GEMM -> PRE-SCALED bf16 out: Hout[r] = dinv[r] * (A[r] @ W)  (bf16)
// v4: 32-row tiles (1563 blocks -> ~6 blocks/CU of work), 256 thr,
// per-thread 2 rows x 8 cols. K-panels of 32; W-panel (16KB) + A-tile
// (32x36 pad, 4.6KB) in LDS, REG-STAGED double buffer: panel p+1 global
// loads issued into registers before compute of panel p (latency hidden
// under ~1024cy of FMA), regs written to LDS after the barrier.
// __launch_bounds__(256,5): VGPR<=102 -> 5 waves/SIMD -> ~20 waves/CU.
// ---------------------------------------------------------------------------
#define XT_STRIDE 36   // f32; rows 8 banks apart, read groups conflict-free

template <bool RELU>
__global__ __launch_bounds__(256, 5) void k_gemm(const float* __restrict__ A,
                                                 const float* __restrict__ W,
                                                 const float* __restrict__ dinv,
                                                 unsigned int* __restrict__ Hout) {
    __shared__ float Wp[32 * 128];          // k-major: Wp4[k*32 + c4]
    __shared__ float Xs[32 * XT_STRIDE];    // [row][k] padded
    int tid = threadIdx.x;
    int cg = tid & 15;    // cols cg*4..+3 and 64+cg*4..+3
    int rg = tid >> 4;    // rows rg*2, rg*2+1
    int row0 = blockIdx.x * 32;

    const float4* W4 = (const float4*)W;
    const float4* A4 = (const float4*)A;
    float4* Wp4 = (float4*)Wp;

    // A-tile load coords: thread -> (row ar, float4-col ac) within panel
    int ar = tid >> 3;          // 0..31
    int ac = tid & 7;           // 0..7 (8 float4 = 32 k)
    int gr_a = row0 + ar;

    float4 acc[2][2];
#pragma unroll
    for (int i = 0; i < 2; ++i) {
        acc[i][0] = make_float4(0.f, 0.f, 0.f, 0.f);
        acc[i][1] = make_float4(0.f, 0.f, 0.f, 0.f);
    }

    // ---- prologue: issue panel-0 loads into registers
    float4 wst[4];
    float4 ast;
#pragma unroll
    for (int i = 0; i < 4; ++i) wst[i] = W4[tid + 256 * i];
    {
        float4 v = make_float4(0.f, 0.f, 0.f, 0.f);
        if (gr_a < N_NODES) v = A4[gr_a * 32 + ac];
        ast = v;
    }

#pragma unroll 1
    for (int p = 0; p < 4; ++p) {
        if (p) __syncthreads();   // previous compute done with LDS
        // write staged regs -> LDS (implicit vmcnt wait on wst/ast)
        if (RELU) {
            ast.x = fmaxf(ast.x, 0.f); ast.y = fmaxf(ast.y, 0.f);
            ast.z = fmaxf(ast.z, 0.f); ast.w = fmaxf(ast.w, 0.f);
        }
#pragma unroll
        for (int i = 0; i < 4; ++i) Wp4[tid + 256 * i] = wst[i];
        *(float4*)(Xs + ar * XT_STRIDE + ac * 4) = ast;
        __syncthreads();

        // issue next panel's loads (fly during compute below)
        if (p < 3) {
#pragma unroll
            for (int i = 0; i < 4; ++i) wst[i] = W4[(p + 1) * 1024 + tid + 256 * i];
            float4 v = make_float4(0.f, 0.f, 0.f, 0.f);
            if (gr_a < N_NODES) v = A4[gr_a * 32 + (p + 1) * 8 + ac];
            ast = v;
        }

        // compute panel p
#pragma unroll
        for (int k0 = 0; k0 < 32; k0 += 4) {
            float4 wv[4][2];
#pragma unroll
            for (int kk = 0; kk < 4; ++kk) {
                wv[kk][0] = Wp4[(k0 + kk) * 32 + cg];
                wv[kk][1] = Wp4[(k0 + kk) * 32 + 16 + cg];
            }
            float4 xv[2];
#pragma unroll
            for (int i = 0; i < 2; ++i)
                xv[i] = *(const float4*)(Xs + (rg * 2 + i) * XT_STRIDE + k0);
#pragma unroll
            for (int i = 0; i < 2; ++i) {
#pragma unroll
                for (int kk = 0; kk < 4; ++kk) {
                    float xs = (kk == 0) ? xv[i].x : (kk == 1) ? xv[i].y
                             : (kk == 2) ? xv[i].z : xv[i].w;
#pragma unroll
                    for (int h = 0; h < 2; ++h) {
                        acc[i][h].x += xs * wv[kk][h].x;
                        acc[i][h].y += xs * wv[kk][h].y;
                        acc[i][h].z += xs * wv[kk][h].z;
                        acc[i][h].w += xs * wv[kk][h].w;
                    }
                }
            }
        }
    }

    // epilogue: dinv pre-scale + bf16 pack
#pragma unroll
    for (int i = 0; i < 2; ++i) {
        int gr = row0 + rg * 2 + i;
        if (gr < N_NODES) {
            float dv = dinv[gr];
            uint2 u0, u1;
            u0.x = packbf2(dv * acc[i][0].x, dv * acc[i][0].y);
            u0.y = packbf2(dv * acc[i][0].z, dv * acc[i][0].w);
            u1.x = packbf2(dv * acc[i][1].x, dv * acc[i][1].y);
            u1.y = packbf2(dv * acc[i][1].z, dv * acc[i][1].w);
            *(uint2*)&Hout[gr * 64 + cg * 2]      = u0;
            *(uint2*)&Hout[gr * 64 + 32 + cg * 2] = u1;
        }
    }
}

// ---------------------------------------------------------------------------
// Fused bucket aggregation (unchanged from round 6): 1024 thr per 128-node
// bucket; block-local CSR in LDS; h pre-scaled so gather is a pure row-sum.
// ---------------------------------------------------------------------------
__device__ __forceinline__ void add8(float* acc, uint4 u) {
    acc[0] += __uint_as_float(u.x << 16);
    acc[1] += __uint_as_float(u.x & 0xffff0000u);
    acc[2] += __uint_as_float(u.y << 16);
    acc[3] += __uint_as_float(u.y & 0xffff0000u);
    acc[4] += __uint_as_float(u.z << 16);
    acc[5] += __uint_as_float(u.z & 0xffff0000u);
    acc[6] += __uint_as_float(u.w << 16);
    acc[7] += __uint_as_float(u.w & 0xffff0000u);
}

template <bool FINAL>
__global__ __launch_bounds__(1024) void k_agg(const uint4* __restrict__ h4,
                                              const int2* __restrict__ tmp,
                                              const int* __restrict__ gcur,
                                              const float* __restrict__ bias,
                                              const float* __restrict__ Wlin,
                                              const float* __restrict__ blin,
                                              float* __restrict__ aggout) {
    __shared__ int   rawsrc[CAPB];
    __shared__ short rawloc[CAPB];
    __shared__ int   lcsr[CAPB];
    __shared__ int   lcnt[128];
    __shared__ int   lbase0[128];
    __shared__ int   lcur[128];
    __shared__ int   stmp[128];

    int b = blockIdx.x, tid = threadIdx.x;
    int cnt = gcur[b];
    if (cnt > CAPB) cnt = CAPB;

    if (tid < 128) { lcnt[tid] = 0; lcur[tid] = 0; }
    __syncthreads();

    for (int i = tid; i < cnt; i += 1024) {
        int2 v = tmp[b * CAPB + i];
        int l = v.y & 127;
        rawsrc[i] = v.x;
        rawloc[i] = (short)l;
        atomicAdd(&lcnt[l], 1);
    }
    __syncthreads();

    // exclusive scan of lcnt -> lbase0 (Hillis-Steele over 128)
    {
        int c = (tid < 128) ? lcnt[tid] : 0;
        if (tid < 128) stmp[tid] = c;
        __syncthreads();
        int v = c;
        for (int d = 1; d < 128; d <<= 1) {
            int w = (tid >= d && tid < 128) ? stmp[tid - d] : 0;
            __syncthreads();
            if (tid < 128) { v += w; stmp[tid] = v; }
            __syncthreads();
        }
        if (tid < 128) lbase0[tid] = v - c;
    }
    __syncthreads();

    for (int i = tid; i < cnt; i += 1024) {
        int l = rawloc[i];
        int p = atomicAdd(&lcur[l], 1);
        lcsr[lbase0[l] + p] = rawsrc[i];
    }
    __syncthreads();

    int wv = tid >> 6, lane = tid & 63, eg = lane >> 4, cq = lane & 15;

    float4 bv0 = ((const float4*)bias)[cq * 2];
    float4 bv1 = ((const float4*)bias)[cq * 2 + 1];
    float4 wl0 = make_float4(0.f, 0.f, 0.f, 0.f), wl1 = wl0;
    float bl = 0.f;
    if (FINAL) {
        wl0 = ((const float4*)Wlin)[cq * 2];
        wl1 = ((const float4*)Wlin)[cq * 2 + 1];
        bl = blin[0];
    }

#pragma unroll 1
    for (int t = 0; t < 8; ++t) {
        int ln = wv * 8 + t;
        int node = b * 128 + ln;
        if (node >= N_NODES) break;   // uniform per wave
        int deg = lcnt[ln];
        int o0 = lbase0[ln], o1 = o0 + deg;

        float acc[8];
#pragma unroll
        for (int j = 0; j < 8; ++j) acc[j] = 0.f;

        int e = o0;
        for (; e + 8 <= o1; e += 8) {
            int s0 = lcsr[e + 2 * eg];
            int s1 = lcsr[e + 2 * eg + 1];
            uint4 u0 = h4[s0 * 16 + cq];
            uint4 u1 = h4[s1 * 16 + cq];
            add8(acc, u0);
            add8(acc, u1);
        }
        {   // tail (< 8 edges)
            int r = o1 - e;
            int b0 = e + 2 * eg;
            if (2 * eg < r)     { int s = lcsr[b0];     add8(acc, h4[s * 16 + cq]); }
            if (2 * eg + 1 < r) { int s = lcsr[b0 + 1]; add8(acc, h4[s * 16 + cq]); }
        }
#pragma unroll
        for (int j = 0; j < 8; ++j) {
            acc[j] += __shfl_xor(acc[j], 16, 64);
            acc[j] += __shfl_xor(acc[j], 32, 64);
        }

        float dv = rsqrtf((float)deg + 1.0f);
        uint4 us = h4[node * 16 + cq];
        float hv[8];
        hv[0] = __uint_as_float(us.x << 16); hv[1] = __uint_as_float(us.x & 0xffff0000u);
        hv[2] = __uint_as_float(us.y << 16); hv[3] = __uint_as_float(us.y & 0xffff0000u);
        hv[4] = __uint_as_float(us.z << 16); hv[5] = __uint_as_float(us.z & 0xffff0000u);
        hv[6] = __uint_as_float(us.w << 16); hv[7] = __uint_as_float(us.w & 0xffff0000u);
        float o[8];
        o[0] = dv * (acc[0] + hv[0]) + bv0.x;
        o[1] = dv * (acc[1] + hv[1]) + bv0.y;
        o[2] = dv * (acc[2] + hv[2]) + bv0.z;
        o[3] = dv * (acc[3] + hv[3]) + bv0.w;
        o[4] = dv * (acc[4] + hv[4]) + bv1.x;
        o[5] = dv * (acc[5] + hv[5]) + bv1.y;
        o[6] = dv * (acc[6] + hv[6]) + bv1.z;
        o[7] = dv * (acc[7] + hv[7]) + bv1.w;

        if (!FINAL) {
            if (eg == 0) {
                float4* out4 = (float4*)aggout;
                out4[node * 32 + cq * 2]     = make_float4(o[0], o[1], o[2], o[3]);
                out4[node * 32 + cq * 2 + 1] = make_float4(o[4], o[5], o[6], o[7]);
            }
        } else {
            float v = fmaxf(o[0], 0.f) * wl0.x + fmaxf(o[1], 0.f) * wl0.y
                    + fmaxf(o[2], 0.f) * wl0.z + fmaxf(o[3], 0.f) * wl0.w
                    + fmaxf(o[4], 0.f) * wl1.x + fmaxf(o[5], 0.f) * wl1.y
                    + fmaxf(o[6], 0.f) * wl1.z + fmaxf(o[7], 0.f) * wl1.w;
            v += __shfl_xor(v, 1, 64);
            v += __shfl_xor(v, 2, 64);
            v += __shfl_xor(v, 4, 64);
            v += __shfl_xor(v, 8, 64);
            if (lane == 0) aggout[node] = v + bl;
        }
    }
}

// ---------------------------------------------------------------------------
extern "C" void kernel_launch(void* const* d_in, const int* in_sizes, int n_in,
                              void* d_out, int out_size, void* d_ws, size_t ws_size,
                              hipStream_t stream) {
    const float* x    = (const float*)d_in[0];
    const int*   ei   = (const int*)d_in[2];
    const float* W1   = (const float*)d_in[4];
    const float* b1   = (const float*)d_in[5];
    const float* W2   = (const float*)d_in[6];
    const float* b2   = (const float*)d_in[7];
    const float* Wlin = (const float*)d_in[8];
    const float* blin = (const float*)d_in[9];
    float* out = (float*)d_out;

    char* ws = (char*)d_ws;
    size_t off = 0;
    auto carve = [&](size_t bytes) -> void* {
        void* p = ws + off;
        off = (off + bytes + 255) & ~(size_t)255;
        return p;
    };
    int*   gcur = (int*)  carve(NBB * sizeof(int));
    float* dinv = (float*)carve(N_NODES * sizeof(float));
    int2*  tmp  = (int2*) carve((size_t)NBB * CAPB * sizeof(int2));   // 8.1 MB
    unsigned int* hbf = (unsigned int*)carve((size_t)N_NODES * 64 * sizeof(unsigned int));
    float* agg  = (float*)carve((size_t)N_NODES * C * sizeof(float));

    const int NB_A = (N_EDGES + CHUNK - 1) / CHUNK;   // 391
    const int NB_G = (N_NODES + 31) / 32;             // 1563

    hipMemsetAsync(gcur, 0, NBB * sizeof(int), stream);

    // edge partition + degrees
    k_binA<<<NB_A, 256, 0, stream>>>(ei, gcur, tmp);
    k_dinv<<<NBB, 256, 0, stream>>>(tmp, gcur, dinv);

    // Layer 1 (h pre-scaled by dinv[row])
    k_gemm<false><<<NB_G, 256, 0, stream>>>(x, W1, dinv, hbf);
    k_agg<false><<<NBB, 1024, 0, stream>>>((const uint4*)hbf, tmp, gcur,
                                           b1, Wlin, blin, agg);
    // Layer 2
    k_gemm<true><<<NB_G, 256, 0, stream>>>(agg, W2, dinv, hbf);
    k_agg<true><<<NBB, 1024, 0, stream>>>((const uint4*)hbf, tmp, gcur,
                                          b2, Wlin, blin, out);
}

// Round 8
// 201.993 us; speedup vs baseline: 1.4313x; 1.4313x over previous
//
#include <hip/hip_runtime.h>
#include <hip/hip_bf16.h>

#define N_NODES 50000
#define N_EDGES 800000
#define C 128

#define NBB   391      // buckets of 128 nodes: bucket = dst >> 7
#define CAPB  2600     // per-bucket capacity (mean 2046, +12 sigma)
#define CHUNK 2048     // edges per binA block

typedef __attribute__((ext_vector_type(8))) short short8v;  // 8 bf16 (4 VGPR)
typedef __attribute__((ext_vector_type(4))) float f32x4;    // MFMA C/D

// ---------------------------------------------------------------------------
// k_binA: single-level radix partition (unchanged from round 6).
// ---------------------------------------------------------------------------
__global__ __launch_bounds__(256) void k_binA(const int* __restrict__ ei,
                                              int* __restrict__ gcur,
                                              int2* __restrict__ tmp) {
    __shared__ int hist[NBB];
    __shared__ int lbase[NBB];
    __shared__ int gbaseL[NBB];
    __shared__ int stmp[256];
    __shared__ int2 buf[CHUNK];
    __shared__ int totalv;

    int tid = threadIdx.x;
    int e0 = blockIdx.x * CHUNK;

    for (int i = tid; i < NBB; i += 256) hist[i] = 0;
    __syncthreads();

    int sarr[8], darr[8], parr[8];
#pragma unroll
    for (int j = 0; j < 8; ++j) {
        int e = e0 + j * 256 + tid;
        darr[j] = -1;
        if (e < N_EDGES) {
            sarr[j] = ei[e];
            int d = ei[N_EDGES + e];
            darr[j] = d;
            parr[j] = atomicAdd(&hist[d >> 7], 1);
        }
    }
    __syncthreads();

    {   // exclusive scan of hist (pairs)
        int i0 = 2 * tid, i1 = 2 * tid + 1;
        int c0 = (i0 < NBB) ? hist[i0] : 0;
        int c1 = (i1 < NBB) ? hist[i1] : 0;
        int c = c0 + c1;
        stmp[tid] = c;
        __syncthreads();
        int v = c;
        for (int d = 1; d < 256; d <<= 1) {
            int w = (tid >= d) ? stmp[tid - d] : 0;
            __syncthreads();
            v += w;
            stmp[tid] = v;
            __syncthreads();
        }
        int excl = v - c;
        if (i0 < NBB) lbase[i0] = excl;
        if (i1 < NBB) lbase[i1] = excl + c0;
        if (tid == 255) totalv = v;
    }
    for (int i = tid; i < NBB; i += 256) {
        int cnt = hist[i];
        int run = (cnt > 0) ? atomicAdd(&gcur[i], cnt) : 0;
        gbaseL[i] = i * CAPB + run;
    }
    __syncthreads();

#pragma unroll
    for (int j = 0; j < 8; ++j) {
        if (darr[j] >= 0) {
            int b = darr[j] >> 7;
            buf[lbase[b] + parr[j]] = make_int2(sarr[j], darr[j]);
        }
    }
    __syncthreads();

    int total = totalv;
    for (int i = tid; i < total; i += 256) {
        int2 v = buf[i];
        int b = v.y >> 7;
        int gpos = gbaseL[b] + (i - lbase[b]);
        if (gpos < (b + 1) * CAPB) tmp[gpos] = v;
    }
}

// ---------------------------------------------------------------------------
// k_dinv: per-node in-degree, dinv = rsqrt(deg+1).
// ---------------------------------------------------------------------------
__global__ __launch_bounds__(256) void k_dinv(const int2* __restrict__ tmp,
                                              const int* __restrict__ gcur,
                                              float* __restrict__ dinv) {
    __shared__ int cnt[128];
    int b = blockIdx.x, tid = threadIdx.x;
    if (tid < 128) cnt[tid] = 0;
    __syncthreads();
    int n = gcur[b];
    if (n > CAPB) n = CAPB;
    for (int i = tid; i < n; i += 256)
        atomicAdd(&cnt[tmp[b * CAPB + i].y & 127], 1);
    __syncthreads();
    int node = b * 128 + tid;
    if (tid < 128 && node < N_NODES)
        dinv[node] = rsqrtf((float)cnt[tid] + 1.0f);
}

// ---------------------------------------------------------------------------
// bf16 pack helpers (RTN)
// ---------------------------------------------------------------------------
__device__ __forceinline__ unsigned int bf16rtn(float f) {
    unsigned int u = __float_as_uint(f);
    return (u + 0x7fffu + ((u >> 16) & 1u)) >> 16;
}
__device__ __forceinline__ unsigned int packbf2(float lo, float hi) {
    return bf16rtn(lo) | (bf16rtn(hi) << 16);
}

// ---------------------------------------------------------------------------
// k_prepW: split W (f32 [k][col]) into Wh + Wl bf16 stored [col][k]
// (= row-major B^T, the layout MFMA B-frags want: lane l holds
// W[kbase..kbase+7][16c + (l&15)], 16 contiguous bytes).
// Wsplit layout: [W1h | W1l | W2h | W2l], 16384 ushort each.
// ---------------------------------------------------------------------------
__global__ void k_prepW(const float* __restrict__ W1, const float* __restrict__ W2,
                        unsigned short* __restrict__ Wsplit) {
    int t = blockIdx.x * 256 + threadIdx.x;   // 0..32767
    if (t >= 32768) return;
    int layer = t >> 14, idx = t & 16383;
    int i = idx >> 7, j = idx & 127;          // i = k (in), j = col (out)
    const float* Wsrc = layer ? W2 : W1;
    float w = Wsrc[i * 128 + j];
    unsigned int h = bf16rtn(w);
    float hf = __uint_as_float(h << 16);
    unsigned int l = bf16rtn(w - hf);
    unsigned short* base = Wsplit + layer * 32768;
    base[j * 128 + i] = (unsigned short)h;
    base[16384 + j * 128 + i] = (unsigned short)l;
}

// ---------------------------------------------------------------------------
// MFMA GEMM (2-term W-split): Hout[r][c] = bf16( dinv[r] * (A[r] @ (Wh+Wl)) )
// Block 512 thr (8 waves), 64-row tile, 782 blocks. Wave w owns col-tile
// cols 16w..16w+15; its 8 B-frags (Wh,Wl x 4 K-steps) live in registers.
// A staged once in LDS as bf16, XOR-swizzled (byte ^= (row&7)<<4) ->
// conflict-free b128 frag reads. 32 MFMA (16x16x32_bf16) per wave.
// Frag layouts (m89/m92-verified family): A: row=l&15, k=(l>>4)*8+j;
// B(^T rows): col=l&15, k=(l>>4)*8+j; D: col=l&15, row=(l>>4)*4+reg.
// ---------------------------------------------------------------------------
template <bool RELU>
__global__ __launch_bounds__(512, 4) void k_gemm(const float* __restrict__ A,
                                                 const unsigned short* __restrict__ Whg,
                                                 const unsigned short* __restrict__ Wlg,
                                                 const float* __restrict__ dinv,
                                                 unsigned short* __restrict__ Hout) {
    __shared__ uint4 Al[64 * 16];   // [64 rows][128 k] bf16, swizzled
    __shared__ float ddv[64];

    int tid = threadIdx.x;
    int row0 = blockIdx.x * 64;
    int wv = tid >> 6, lane = tid & 63;
    int col = wv * 16 + (lane & 15);
    int kq = lane >> 4;               // k-quarter: k = ks*32 + kq*8 + j

    // B-frags from global split-W tables (L2-resident, 64 KB total)
    const uint4* Bh4 = (const uint4*)Whg;
    const uint4* Bl4 = (const uint4*)Wlg;
    short8v bh[4], bl[4];
#pragma unroll
    for (int ks = 0; ks < 4; ++ks) {
        uint4 uh = Bh4[col * 16 + ks * 4 + kq];
        uint4 ul = Bl4[col * 16 + ks * 4 + kq];
        bh[ks] = *reinterpret_cast<short8v*>(&uh);
        bl[ks] = *reinterpret_cast<short8v*>(&ul);
    }

    // Stage A tile: 64 rows x 128 k f32 -> bf16, swizzled. 2 passes.
#pragma unroll
    for (int pass = 0; pass < 2; ++pass) {
        int row = (tid >> 4) + pass * 32;
        int o = tid & 15;             // k-octet: k = 8o..8o+7
        int gr = row0 + row;
        float4 v0 = make_float4(0.f, 0.f, 0.f, 0.f), v1 = v0;
        if (gr < N_NODES) {
            const float4* A4 = (const float4*)A;
            v0 = A4[gr * 32 + o * 2];
            v1 = A4[gr * 32 + o * 2 + 1];
        }
        if (RELU) {
            v0.x = fmaxf(v0.x, 0.f); v0.y = fmaxf(v0.y, 0.f);
            v0.z = fmaxf(v0.z, 0.f); v0.w = fmaxf(v0.w, 0.f);
            v1.x = fmaxf(v1.x, 0.f); v1.y = fmaxf(v1.y, 0.f);
            v1.z = fmaxf(v1.z, 0.f); v1.w = fmaxf(v1.w, 0.f);
        }
        uint4 u;
        u.x = packbf2(v0.x, v0.y);
        u.y = packbf2(v0.z, v0.w);
        u.z = packbf2(v1.x, v1.y);
        u.w = packbf2(v1.z, v1.w);
        int byte = (row * 256 + o * 16) ^ ((row & 7) << 4);
        Al[byte >> 4] = u;
    }
    if (tid < 64) {
        int gr = row0 + tid;
        ddv[tid] = (gr < N_NODES) ? dinv[gr] : 0.f;
    }
    __syncthreads();

    f32x4 acc[4];
#pragma unroll
    for (int st = 0; st < 4; ++st) acc[st] = (f32x4){0.f, 0.f, 0.f, 0.f};

#pragma unroll
    for (int st = 0; st < 4; ++st) {
        int rowl = st * 16 + (lane & 15);
        int rbase = rowl * 256;
        int swz = (rowl & 7) << 4;
#pragma unroll
        for (int ks = 0; ks < 4; ++ks) {
            int byte = (rbase + ks * 64 + kq * 16) ^ swz;
            uint4 ua = Al[byte >> 4];
            short8v a = *reinterpret_cast<short8v*>(&ua);
            acc[st] = __builtin_amdgcn_mfma_f32_16x16x32_bf16(a, bh[ks], acc[st], 0, 0, 0);
            acc[st] = __builtin_amdgcn_mfma_f32_16x16x32_bf16(a, bl[ks], acc[st], 0, 0, 0);
        }
    }

    // Epilogue: D lane l reg r -> row (l>>4)*4+r (within stripe), col.
#pragma unroll
    for (int st = 0; st < 4; ++st) {
#pragma unroll
        for (int r = 0; r < 4; ++r) {
            int rowl = st * 16 + kq * 4 + r;
            int gr = row0 + rowl;
            if (gr < N_NODES) {
                float dv = ddv[rowl];
                Hout[gr * 128 + col] = (unsigned short)bf16rtn(dv * acc[st][r]);
            }
        }
    }
}

// ---------------------------------------------------------------------------
// Fused bucket aggregation (unchanged from round 6): 1024 thr per 128-node
// bucket; block-local CSR in LDS; h pre-scaled so gather is a pure row-sum.
// ---------------------------------------------------------------------------
__device__ __forceinline__ void add8(float* acc, uint4 u) {
    acc[0] += __uint_as_float(u.x << 16);
    acc[1] += __uint_as_float(u.x & 0xffff0000u);
    acc[2] += __uint_as_float(u.y << 16);
    acc[3] += __uint_as_float(u.y & 0xffff0000u);
    acc[4] += __uint_as_float(u.z << 16);
    acc[5] += __uint_as_float(u.z & 0xffff0000u);
    acc[6] += __uint_as_float(u.w << 16);
    acc[7] += __uint_as_float(u.w & 0xffff0000u);
}

template <bool FINAL>
__global__ __launch_bounds__(1024) void k_agg(const uint4* __restrict__ h4,
                                              const int2* __restrict__ tmp,
                                              const int* __restrict__ gcur,
                                              const float* __restrict__ bias,
                                              const float* __restrict__ Wlin,
                                              const float* __restrict__ blin,
                                              float* __restrict__ aggout) {
    __shared__ int   rawsrc[CAPB];
    __shared__ short rawloc[CAPB];
    __shared__ int   lcsr[CAPB];
    __shared__ int   lcnt[128];
    __shared__ int   lbase0[128];
    __shared__ int   lcur[128];
    __shared__ int   stmp[128];

    int b = blockIdx.x, tid = threadIdx.x;
    int cnt = gcur[b];
    if (cnt > CAPB) cnt = CAPB;

    if (tid < 128) { lcnt[tid] = 0; lcur[tid] = 0; }
    __syncthreads();

    for (int i = tid; i < cnt; i += 1024) {
        int2 v = tmp[b * CAPB + i];
        int l = v.y & 127;
        rawsrc[i] = v.x;
        rawloc[i] = (short)l;
        atomicAdd(&lcnt[l], 1);
    }
    __syncthreads();

    {   // exclusive scan of lcnt -> lbase0
        int c = (tid < 128) ? lcnt[tid] : 0;
        if (tid < 128) stmp[tid] = c;
        __syncthreads();
        int v = c;
        for (int d = 1; d < 128; d <<= 1) {
            int w = (tid >= d && tid < 128) ? stmp[tid - d] : 0;
            __syncthreads();
            if (tid < 128) { v += w; stmp[tid] = v; }
            __syncthreads();
        }
        if (tid < 128) lbase0[tid] = v - c;
    }
    __syncthreads();

    for (int i = tid; i < cnt; i += 1024) {
        int l = rawloc[i];
        int p = atomicAdd(&lcur[l], 1);
        lcsr[lbase0[l] + p] = rawsrc[i];
    }
    __syncthreads();

    int wv = tid >> 6, lane = tid & 63, eg = lane >> 4, cq = lane & 15;

    float4 bv0 = ((const float4*)bias)[cq * 2];
    float4 bv1 = ((const float4*)bias)[cq * 2 + 1];
    float4 wl0 = make_float4(0.f, 0.f, 0.f, 0.f), wl1 = wl0;
    float bl = 0.f;
    if (FINAL) {
        wl0 = ((const float4*)Wlin)[cq * 2];
        wl1 = ((const float4*)Wlin)[cq * 2 + 1];
        bl = blin[0];
    }

#pragma unroll 1
    for (int t = 0; t < 8; ++t) {
        int ln = wv * 8 + t;
        int node = b * 128 + ln;
        if (node >= N_NODES) break;   // uniform per wave
        int deg = lcnt[ln];
        int o0 = lbase0[ln], o1 = o0 + deg;

        float acc[8];
#pragma unroll
        for (int j = 0; j < 8; ++j) acc[j] = 0.f;

        int e = o0;
        for (; e + 8 <= o1; e += 8) {
            int s0 = lcsr[e + 2 * eg];
            int s1 = lcsr[e + 2 * eg + 1];
            uint4 u0 = h4[s0 * 16 + cq];
            uint4 u1 = h4[s1 * 16 + cq];
            add8(acc, u0);
            add8(acc, u1);
        }
        {   // tail (< 8 edges)
            int r = o1 - e;
            int b0 = e + 2 * eg;
            if (2 * eg < r)     { int s = lcsr[b0];     add8(acc, h4[s * 16 + cq]); }
            if (2 * eg + 1 < r) { int s = lcsr[b0 + 1]; add8(acc, h4[s * 16 + cq]); }
        }
#pragma unroll
        for (int j = 0; j < 8; ++j) {
            acc[j] += __shfl_xor(acc[j], 16, 64);
            acc[j] += __shfl_xor(acc[j], 32, 64);
        }

        float dv = rsqrtf((float)deg + 1.0f);
        uint4 us = h4[node * 16 + cq];
        float hv[8];
        hv[0] = __uint_as_float(us.x << 16); hv[1] = __uint_as_float(us.x & 0xffff0000u);
        hv[2] = __uint_as_float(us.y << 16); hv[3] = __uint_as_float(us.y & 0xffff0000u);
        hv[4] = __uint_as_float(us.z << 16); hv[5] = __uint_as_float(us.z & 0xffff0000u);
        hv[6] = __uint_as_float(us.w << 16); hv[7] = __uint_as_float(us.w & 0xffff0000u);
        float o[8];
        o[0] = dv * (acc[0] + hv[0]) + bv0.x;
        o[1] = dv * (acc[1] + hv[1]) + bv0.y;
        o[2] = dv * (acc[2] + hv[2]) + bv0.z;
        o[3] = dv * (acc[3] + hv[3]) + bv0.w;
        o[4] = dv * (acc[4] + hv[4]) + bv1.x;
        o[5] = dv * (acc[5] + hv[5]) + bv1.y;
        o[6] = dv * (acc[6] + hv[6]) + bv1.z;
        o[7] = dv * (acc[7] + hv[7]) + bv1.w;

        if (!FINAL) {
            if (eg == 0) {
                float4* out4 = (float4*)aggout;
                out4[node * 32 + cq * 2]     = make_float4(o[0], o[1], o[2], o[3]);
                out4[node * 32 + cq * 2 + 1] = make_float4(o[4], o[5], o[6], o[7]);
            }
        } else {
            float v = fmaxf(o[0], 0.f) * wl0.x + fmaxf(o[1], 0.f) * wl0.y
                    + fmaxf(o[2], 0.f) * wl0.z + fmaxf(o[3], 0.f) * wl0.w
                    + fmaxf(o[4], 0.f) * wl1.x + fmaxf(o[5], 0.f) * wl1.y
                    + fmaxf(o[6], 0.f) * wl1.z + fmaxf(o[7], 0.f) * wl1.w;
            v += __shfl_xor(v, 1, 64);
            v += __shfl_xor(v, 2, 64);
            v += __shfl_xor(v, 4, 64);
            v += __shfl_xor(v, 8, 64);
            if (lane == 0) aggout[node] = v + bl;
        }
    }
}

// ---------------------------------------------------------------------------
extern "C" void kernel_launch(void* const* d_in, const int* in_sizes, int n_in,
                              void* d_out, int out_size, void* d_ws, size_t ws_size,
                              hipStream_t stream) {
    const float* x    = (const float*)d_in[0];
    const int*   ei   = (const int*)d_in[2];
    const float* W1   = (const float*)d_in[4];
    const float* b1   = (const float*)d_in[5];
    const float* W2   = (const float*)d_in[6];
    const float* b2   = (const float*)d_in[7];
    const float* Wlin = (const float*)d_in[8];
    const float* blin = (const float*)d_in[9];
    float* out = (float*)d_out;

    char* ws = (char*)d_ws;
    size_t off = 0;
    auto carve = [&](size_t bytes) -> void* {
        void* p = ws + off;
        off = (off + bytes + 255) & ~(size_t)255;
        return p;
    };
    int*   gcur = (int*)  carve(NBB * sizeof(int));
    float* dinv = (float*)carve(N_NODES * sizeof(float));
    int2*  tmp  = (int2*) carve((size_t)NBB * CAPB * sizeof(int2));   // 8.1 MB
    unsigned short* hbf = (unsigned short*)carve((size_t)N_NODES * C * sizeof(unsigned short));
    float* agg  = (float*)carve((size_t)N_NODES * C * sizeof(float));
    unsigned short* wsplit = (unsigned short*)carve(4 * 16384 * sizeof(unsigned short));

    const int NB_A = (N_EDGES + CHUNK - 1) / CHUNK;   // 391
    const int NB_G = (N_NODES + 63) / 64;             // 782

    hipMemsetAsync(gcur, 0, NBB * sizeof(int), stream);

    // W split tables + edge partition + degrees
    k_prepW<<<128, 256, 0, stream>>>(W1, W2, wsplit);
    k_binA<<<NB_A, 256, 0, stream>>>(ei, gcur, tmp);
    k_dinv<<<NBB, 256, 0, stream>>>(tmp, gcur, dinv);

    const unsigned short* W1h = wsplit;
    const unsigned short* W1l = wsplit + 16384;
    const unsigned short* W2h = wsplit + 32768;
    const unsigned short* W2l = wsplit + 49152;

    // Layer 1 (h pre-scaled by dinv[row])
    k_gemm<false><<<NB_G, 512, 0, stream>>>(x, W1h, W1l, dinv, hbf);
    k_agg<false><<<NBB, 1024, 0, stream>>>((const uint4*)hbf, tmp, gcur,
                                           b1, Wlin, blin, agg);
    // Layer 2
    k_gemm<true><<<NB_G, 512, 0, stream>>>(agg, W2h, W2l, dinv, hbf);
    k_agg<true><<<NBB, 1024, 0, stream>>>((const uint4*)hbf, tmp, gcur,
                                          b2, Wlin, blin, out);
}